// Round 14
// baseline (205.313 us; speedup 1.0000x reference)
//
#include <hip/hip_runtime.h>
#include <hip/hip_fp16.h>

#define N_NODES 100000
#define N_EDGES 1600000
#define N_GRAPHS 64

// ELL build (cap 64; max deg_in <= 48 proven R4). fp16 feature buffers
// (fp32 compute) validated R13: absmax 2.4e-4 << 2.1e-3. R14: (1) layer1 back
// to 2 lanes/node (R13 dropped it to 6 waves/CU -- R5 occupancy law); (2) p
// padded to 16 halfs = 32B row = 3.2MB (still < 4MiB per-XCD L2) so layer3
// gathers 2xuint4 instead of 5x4B: issues 8M -> 3.2M. Laws: random-op count
// sets scatter cost (R2-R5); per-XCD L2 residency sets gather cost (R8/R9);
// occupancy sets latency-bound kernel cost (R5/R13); no __threadfence in fat
// grids (R9); traffic cuts alone are neutral (R12).
#define NCHUNK 128
#define CHUNK_E (N_EDGES / NCHUNK)   // 12500
#define NRANGE 2
#define RANGE_N (N_NODES / NRANGE)   // 50000
#define ELL_CAP 64                   // power of 2: start = i<<6
#define SCAN_BLK 256

union H2I { __half2 h2; unsigned int u; };

__device__ inline void acc8h(float* a, uint4 v) {   // 8 halfs -> a[0..8) +=
    H2I t;
    t.u = v.x; float2 f = __half22float2(t.h2); a[0] += f.x; a[1] += f.y;
    t.u = v.y; f = __half22float2(t.h2);        a[2] += f.x; a[3] += f.y;
    t.u = v.z; f = __half22float2(t.h2);        a[4] += f.x; a[5] += f.y;
    t.u = v.w; f = __half22float2(t.h2);        a[6] += f.x; a[7] += f.y;
}

__device__ inline void acc4h(float* a, uint2 v) {   // 4 halfs -> a[0..4) +=
    H2I t;
    t.u = v.x; float2 f = __half22float2(t.h2); a[0] += f.x; a[1] += f.y;
    t.u = v.y; f = __half22float2(t.h2);        a[2] += f.x; a[3] += f.y;
}

// ---------------- fused histogram: dst + src -> packed-u8 partial counts ----------
__global__ __launch_bounds__(1024) void
hist_kernel(const int* __restrict__ dst, const int* __restrict__ src,
            unsigned char* __restrict__ pin8, unsigned char* __restrict__ pout8) {
    __shared__ unsigned int hin[RANGE_N / 4];    // 50KB
    __shared__ unsigned int hout[RANGE_N / 4];   // 50KB
    int c = blockIdx.x >> 1;
    int r = blockIdx.x & 1;
    for (int k = threadIdx.x; k < RANGE_N / 4; k += blockDim.x) { hin[k] = 0; hout[k] = 0; }
    __syncthreads();
    int lo = r * RANGE_N;
    const int4* d4 = (const int4*)(dst + c * CHUNK_E);
    const int4* s4 = (const int4*)(src + c * CHUNK_E);
    for (int k = threadIdx.x; k < CHUNK_E / 4; k += blockDim.x) {
        int4 v = d4[k];
        int d0 = v.x - lo, d1 = v.y - lo, d2 = v.z - lo, d3 = v.w - lo;
        if ((unsigned)d0 < RANGE_N) atomicAdd(&hin[d0 >> 2], 1u << (8 * (d0 & 3)));
        if ((unsigned)d1 < RANGE_N) atomicAdd(&hin[d1 >> 2], 1u << (8 * (d1 & 3)));
        if ((unsigned)d2 < RANGE_N) atomicAdd(&hin[d2 >> 2], 1u << (8 * (d2 & 3)));
        if ((unsigned)d3 < RANGE_N) atomicAdd(&hin[d3 >> 2], 1u << (8 * (d3 & 3)));
        int4 s = s4[k];
        int s0 = s.x - lo, s1 = s.y - lo, s2 = s.z - lo, s3 = s.w - lo;
        if ((unsigned)s0 < RANGE_N) atomicAdd(&hout[s0 >> 2], 1u << (8 * (s0 & 3)));
        if ((unsigned)s1 < RANGE_N) atomicAdd(&hout[s1 >> 2], 1u << (8 * (s1 & 3)));
        if ((unsigned)s2 < RANGE_N) atomicAdd(&hout[s2 >> 2], 1u << (8 * (s2 & 3)));
        if ((unsigned)s3 < RANGE_N) atomicAdd(&hout[s3 >> 2], 1u << (8 * (s3 & 3)));
    }
    __syncthreads();
    unsigned int* pi = (unsigned int*)(pin8 + (size_t)c * N_NODES + lo);
    unsigned int* po = (unsigned int*)(pout8 + (size_t)c * N_NODES + lo);
    for (int k = threadIdx.x; k < RANGE_N / 4; k += blockDim.x) { pi[k] = hin[k]; po[k] = hout[k]; }
}

// ------- per-node chunk-exclusive prefix (u8 in place) + cnt_in/inv_in (+ zero gsum) ----
__global__ void chunkscan_kernel(unsigned char* __restrict__ pin8, int* __restrict__ cnt_in,
                                 float* __restrict__ inv_in, float* __restrict__ gz, int n) {
    if (blockIdx.x == 0) {
        for (int k = threadIdx.x; k < N_GRAPHS * 10 + N_GRAPHS; k += SCAN_BLK) gz[k] = 0.0f;
    }
    int i = blockIdx.x * SCAN_BLK + threadIdx.x;
    if (i >= n) return;
    int s = 0;
#pragma unroll 16
    for (int c = 0; c < NCHUNK; c++) {
        size_t off = (size_t)c * N_NODES + i;
        int v = pin8[off];
        pin8[off] = (unsigned char)s;
        s += v;
    }
    cnt_in[i] = s;
    inv_in[i] = 1.0f / sqrtf(fmaxf((float)s, 1.0f));
}

// ---- place into ELL rows via dual-u16 packed LDS cursors + outdeg/prescale tail ----
__global__ __launch_bounds__(1024) void
place_kernel(const int* __restrict__ src, const int* __restrict__ dst,
             const unsigned char* __restrict__ pin8, int* __restrict__ ell,
             const unsigned char* __restrict__ pout8, const float* __restrict__ x,
             float* __restrict__ inv_out, __half* __restrict__ xs) {
    __shared__ unsigned int cur[RANGE_N / 2];   // dual u16 cursors, 100KB
    int c = blockIdx.x >> 1;
    int r = blockIdx.x & 1;
    int lo = r * RANGE_N;
    const unsigned char* p = pin8 + (size_t)c * N_NODES + lo;
    for (int k = threadIdx.x; k < RANGE_N / 2; k += blockDim.x)
        cur[k] = (unsigned int)p[2 * k] | ((unsigned int)p[2 * k + 1] << 16);
    __syncthreads();
    const int4* d4 = (const int4*)(dst + c * CHUNK_E);
    const int4* s4 = (const int4*)(src + c * CHUNK_E);
    for (int k = threadIdx.x; k < CHUNK_E / 4; k += blockDim.x) {
        int4 dv = d4[k];
        int4 sv = s4[k];
        int d[4] = {dv.x - lo, dv.y - lo, dv.z - lo, dv.w - lo};
        int sarr[4] = {sv.x, sv.y, sv.z, sv.w};
#pragma unroll
        for (int q = 0; q < 4; q++) {
            int dd = d[q];
            if ((unsigned)dd < RANGE_N) {
                unsigned int sh = 16u * (dd & 1);
                unsigned int old = atomicAdd(&cur[dd >> 1], 1u << sh);
                int prefix = (old >> sh) & 0xFFFF;
                ell[((lo + dd) << 6) + prefix] = sarr[q];
            }
        }
    }
    int i = blockIdx.x * blockDim.x + threadIdx.x;
    if (i < N_NODES) {
        int sd = 0;
#pragma unroll 16
        for (int cc = 0; cc < NCHUNK; cc++) sd += pout8[(size_t)cc * N_NODES + i];
        float io = 1.0f / sqrtf(fmaxf((float)sd, 1.0f));
        inv_out[i] = io;
        const float4* x4 = (const float4*)x;
        float4 a = x4[i * 2], b = x4[i * 2 + 1];
        H2I q0, q1, q2, q3;
        q0.h2 = __floats2half2_rn(a.x * io, a.y * io);
        q1.h2 = __floats2half2_rn(a.z * io, a.w * io);
        q2.h2 = __floats2half2_rn(b.x * io, b.y * io);
        q3.h2 = __floats2half2_rn(b.z * io, b.w * io);
        uint4 w = {q0.u, q1.u, q2.u, q3.u};
        ((uint4*)xs)[i] = w;
    }
}

// ---- layer 1: 2 lanes/node (uint2 = 4 halfs each), LDS tile, @W1+b1, relu, *inv_out ----
// 256 thr = 128 nodes/block -> 782 blocks, 12 waves/CU (R13's 1-thread/node was 6).
__global__ __launch_bounds__(256) void
layer1_kernel(const __half* __restrict__ xs, const int* __restrict__ cnt_in,
              const int* __restrict__ ell,
              const float* __restrict__ inv_in, const float* __restrict__ inv_out,
              const float* __restrict__ W1, const float* __restrict__ b1,
              __half* __restrict__ hout) {
    __shared__ float sW[8 * 16];
    __shared__ float sb[16];
    __shared__ float tile[128 * 8];
    if (threadIdx.x < 128) sW[threadIdx.x] = W1[threadIdx.x];
    if (threadIdx.x < 16) sb[threadIdx.x] = b1[threadIdx.x];
    int ii = threadIdx.x >> 1, f = threadIdx.x & 1;
    int i = blockIdx.x * 128 + ii;
    const uint2* xsu = (const uint2*)xs;   // node row = 2 uint2
    float a[4] = {0.f, 0.f, 0.f, 0.f};
    if (i < N_NODES) {
        int start = i << 6, deg = cnt_in[i];
        int k = 0;
        for (; k + 7 < deg; k += 8) {   // 8 uint2 gathers in flight
            int4 I0 = *(const int4*)(ell + start + k);
            int4 I1 = *(const int4*)(ell + start + k + 4);
            uint2 v0 = xsu[I0.x * 2 + f], v1 = xsu[I0.y * 2 + f];
            uint2 v2 = xsu[I0.z * 2 + f], v3 = xsu[I0.w * 2 + f];
            uint2 v4 = xsu[I1.x * 2 + f], v5 = xsu[I1.y * 2 + f];
            uint2 v6 = xsu[I1.z * 2 + f], v7 = xsu[I1.w * 2 + f];
            acc4h(a, v0); acc4h(a, v1); acc4h(a, v2); acc4h(a, v3);
            acc4h(a, v4); acc4h(a, v5); acc4h(a, v6); acc4h(a, v7);
        }
        for (; k < deg; k++) acc4h(a, xsu[ell[start + k] * 2 + f]);
        float inv = inv_in[i];
#pragma unroll
        for (int m = 0; m < 4; m++) a[m] *= inv;
    }
    float4 t = {a[0], a[1], a[2], a[3]};
    ((float4*)tile)[ii * 2 + f] = t;
    __syncthreads();
#pragma unroll
    for (int rep = 0; rep < 8; rep++) {   // 128 nodes x 16 outputs
        int idx = threadIdx.x + rep * 256;
        int i2 = idx >> 4, j = idx & 15;
        int gi = blockIdx.x * 128 + i2;
        if (gi < N_NODES) {
            float o = sb[j];
#pragma unroll
            for (int m = 0; m < 8; m++) o += tile[i2 * 8 + m] * sW[m * 16 + j];
            hout[gi * 16 + j] = __float2half(fmaxf(o, 0.0f) * inv_out[gi]);
        }
    }
}

// ---- layer 2: gather fp16 h (2 lanes/node x uint4) + relu((.)@W2+b2)@W3, *inv_out ----
// p output fp16, PADDED stride 16 halfs (32B row, 3.2MB: per-XCD L2 resident).
__global__ __launch_bounds__(256) void
layer2_kernel(const __half* __restrict__ h, const int* __restrict__ cnt_in,
              const int* __restrict__ ell,
              const float* __restrict__ inv_in, const float* __restrict__ inv_out,
              const float* __restrict__ W2, const float* __restrict__ b2,
              const float* __restrict__ W3, __half* __restrict__ pout) {
    __shared__ float sW2[16 * 32];
    __shared__ float sb2[32];
    __shared__ float sW3[32 * 10];
    __shared__ float tile[128 * 16];    // 8 KB
    __shared__ float otile[128 * 33];   // 16.9 KB, +1 pad
    for (int k = threadIdx.x; k < 512; k += 256) sW2[k] = W2[k];
    if (threadIdx.x < 32) sb2[threadIdx.x] = b2[threadIdx.x];
    for (int k = threadIdx.x; k < 320; k += 256) sW3[k] = W3[k];
    int ii = threadIdx.x >> 1, f = threadIdx.x & 1;   // 2 lanes/node, uint4 each
    int i = blockIdx.x * 128 + ii;
    const uint4* hq = (const uint4*)h;
    float a[8] = {0.f, 0.f, 0.f, 0.f, 0.f, 0.f, 0.f, 0.f};
    if (i < N_NODES) {
        int start = i << 6, deg = cnt_in[i];
        int k = 0;
        for (; k + 7 < deg; k += 8) {
            int4 I0 = *(const int4*)(ell + start + k);
            int4 I1 = *(const int4*)(ell + start + k + 4);
            uint4 v0 = hq[I0.x * 2 + f], v1 = hq[I0.y * 2 + f];
            uint4 v2 = hq[I0.z * 2 + f], v3 = hq[I0.w * 2 + f];
            uint4 v4 = hq[I1.x * 2 + f], v5 = hq[I1.y * 2 + f];
            uint4 v6 = hq[I1.z * 2 + f], v7 = hq[I1.w * 2 + f];
            acc8h(a, v0); acc8h(a, v1); acc8h(a, v2); acc8h(a, v3);
            acc8h(a, v4); acc8h(a, v5); acc8h(a, v6); acc8h(a, v7);
        }
        for (; k < deg; k++) acc8h(a, hq[ell[start + k] * 2 + f]);
        float inv = inv_in[i];
#pragma unroll
        for (int m = 0; m < 8; m++) a[m] *= inv;
    }
    float4 t0 = {a[0], a[1], a[2], a[3]}, t1 = {a[4], a[5], a[6], a[7]};
    ((float4*)tile)[ii * 4 + f * 2] = t0;
    ((float4*)tile)[ii * 4 + f * 2 + 1] = t1;
    __syncthreads();
#pragma unroll
    for (int rep = 0; rep < 16; rep++) {   // 128 nodes x 32 hidden
        int idx = threadIdx.x + rep * 256;
        int i2 = idx >> 5, kk = idx & 31;
        if (blockIdx.x * 128 + i2 < N_NODES) {
            float o = sb2[kk];
#pragma unroll
            for (int m = 0; m < 16; m++) o += tile[i2 * 16 + m] * sW2[m * 32 + kk];
            otile[i2 * 33 + kk] = fmaxf(o, 0.0f);
        }
    }
    __syncthreads();
#pragma unroll
    for (int rep = 0; rep < 4; rep++) {   // 128 nodes x 8 half2 (pairs 5-7 zero pad)
        int idx = threadIdx.x + rep * 256;
        int i2 = idx >> 3, jp = idx & 7;
        int gi = blockIdx.x * 128 + i2;
        if (gi < N_NODES) {
            H2I q;
            if (jp < 5) {
                int j0 = 2 * jp, j1 = j0 + 1;
                float p0 = 0.0f, p1 = 0.0f;
#pragma unroll
                for (int k2 = 0; k2 < 32; k2++) {
                    float ov = otile[i2 * 33 + k2];
                    p0 += ov * sW3[k2 * 10 + j0];
                    p1 += ov * sW3[k2 * 10 + j1];
                }
                float io = inv_out[gi];
                q.h2 = __floats2half2_rn(p0 * io, p1 * io);
            } else {
                q.u = 0;
            }
            ((unsigned int*)pout)[gi * 8 + jp] = q.u;
        }
    }
}

// ---- layer 3: gather fp16 p (2 lanes/node x uint4, 32B padded row) + *inv_in + b3
// ---- + LDS graph mean + sparse global-atomic flush (no fence/ticket) ----
__global__ __launch_bounds__(1024) void
layer3_kernel(const __half* __restrict__ p, const int* __restrict__ cnt_in,
              const int* __restrict__ ell,
              const float* __restrict__ inv_in, const float* __restrict__ b3,
              const int* __restrict__ gid, float* __restrict__ gsum,
              float* __restrict__ gcnt) {
    __shared__ float sb3[10];
    __shared__ float lsum[N_GRAPHS * 10];
    __shared__ float lcnt[N_GRAPHS];
    if (threadIdx.x < 10) sb3[threadIdx.x] = b3[threadIdx.x];
    for (int k = threadIdx.x; k < N_GRAPHS * 10; k += 1024) lsum[k] = 0.0f;
    if (threadIdx.x < N_GRAPHS) lcnt[threadIdx.x] = 0.0f;
    __syncthreads();
    int ii = threadIdx.x >> 1, f = threadIdx.x & 1;   // 2 lanes/node, uint4 each
    int i = blockIdx.x * 512 + ii;
    if (i < N_NODES) {
        const uint4* pq = (const uint4*)p;   // node row = 2 uint4 (16 halfs, 10 real)
        float a[8] = {0.f, 0.f, 0.f, 0.f, 0.f, 0.f, 0.f, 0.f};
        int start = i << 6, deg = cnt_in[i];
        int k = 0;
        for (; k + 7 < deg; k += 8) {
            int4 I0 = *(const int4*)(ell + start + k);
            int4 I1 = *(const int4*)(ell + start + k + 4);
            uint4 v0 = pq[I0.x * 2 + f], v1 = pq[I0.y * 2 + f];
            uint4 v2 = pq[I0.z * 2 + f], v3 = pq[I0.w * 2 + f];
            uint4 v4 = pq[I1.x * 2 + f], v5 = pq[I1.y * 2 + f];
            uint4 v6 = pq[I1.z * 2 + f], v7 = pq[I1.w * 2 + f];
            acc8h(a, v0); acc8h(a, v1); acc8h(a, v2); acc8h(a, v3);
            acc8h(a, v4); acc8h(a, v5); acc8h(a, v6); acc8h(a, v7);
        }
        for (; k < deg; k++) acc8h(a, pq[ell[start + k] * 2 + f]);
        float inv = inv_in[i];
        int g = gid[i];
        if (f == 0) {   // features 0..7
#pragma unroll
            for (int c = 0; c < 8; c++)
                atomicAdd(&lsum[g * 10 + c], a[c] * inv + sb3[c]);
        } else {        // features 8,9 (halfs 10..15 are zero pad)
            atomicAdd(&lsum[g * 10 + 8], a[0] * inv + sb3[8]);
            atomicAdd(&lsum[g * 10 + 9], a[1] * inv + sb3[9]);
            atomicAdd(&lcnt[g], 1.0f);
        }
    }
    __syncthreads();
    for (int k = threadIdx.x; k < N_GRAPHS * 10; k += 1024) {
        float v = lsum[k];
        if (v != 0.0f) atomicAdd(&gsum[k], v);
    }
    if (threadIdx.x < N_GRAPHS) {
        float v = lcnt[threadIdx.x];
        if (v != 0.0f) atomicAdd(&gcnt[threadIdx.x], v);
    }
}

__global__ void finalize_kernel(const float* __restrict__ gsum, const float* __restrict__ gcnt,
                                float* __restrict__ out) {
    int t = blockIdx.x * blockDim.x + threadIdx.x;
    if (t < N_GRAPHS * 10) {
        int g = t / 10;
        out[t] = gsum[t] / fmaxf(gcnt[g], 1.0f);
    }
}

extern "C" void kernel_launch(void* const* d_in, const int* in_sizes, int n_in,
                              void* d_out, int out_size, void* d_ws, size_t ws_size,
                              hipStream_t stream) {
    const float* n_feat = (const float*)d_in[0];  // [N,8]
    const int*   src    = (const int*)d_in[1];    // [E]
    const int*   dst    = (const int*)d_in[2];    // [E]
    const int*   gid    = (const int*)d_in[3];    // [N]
    const float* W1     = (const float*)d_in[4];  // [8,16]
    const float* b1     = (const float*)d_in[5];
    const float* W2     = (const float*)d_in[6];  // [16,32]
    const float* b2     = (const float*)d_in[7];
    const float* W3     = (const float*)d_in[8];  // [32,10]
    const float* b3     = (const float*)d_in[9];
    float* out = (float*)d_out;

    // ---- workspace layout (~60 MB of 256 MiB) ----
    // floats: inv_out(N) | inv_in(N) | bufA h-fp16(16N halfs = 8N f) |
    //         bufB xs fp16(8N halfs)/p fp16(16N halfs = 8N f) | gsum(640) | gcnt(64)
    // ints:   cnt_in(N) | ell(64N)
    // u8:     pin8(128N) | pout8(128N)
    float* ws      = (float*)d_ws;
    float* inv_out = ws;
    float* inv_in  = ws + N_NODES;
    __half* bufA   = (__half*)(ws + 2 * N_NODES);    // h: 16N halfs
    __half* bufB   = (__half*)(ws + 10 * N_NODES);   // xs: 8N halfs / p: 16N halfs
    float* gsum    = ws + 18 * N_NODES;
    float* gcnt    = gsum + N_GRAPHS * 10;
    int* cnt_in    = (int*)(gcnt + N_GRAPHS);
    int* ell       = cnt_in + N_NODES;                          // 64N ints
    unsigned char* pin8  = (unsigned char*)(ell + (size_t)ELL_CAP * N_NODES);
    unsigned char* pout8 = pin8 + (size_t)NCHUNK * N_NODES;

    const int BIGBLK = 1024;
    const int NPARTS = (N_NODES + SCAN_BLK - 1) / SCAN_BLK;  // 391
    const int TGRID = NCHUNK * NRANGE;                        // 256

    // ---- atomic-free graph build, no scan (3 dispatches) ----
    hist_kernel<<<TGRID, BIGBLK, 0, stream>>>(dst, src, pin8, pout8);
    chunkscan_kernel<<<NPARTS, SCAN_BLK, 0, stream>>>(pin8, cnt_in, inv_in, gsum, N_NODES);
    place_kernel<<<TGRID, BIGBLK, 0, stream>>>(src, dst, pin8, ell, pout8, n_feat,
                                               inv_out, bufB);

    // ---- three fused layers + finalize (4 dispatches) ----
    layer1_kernel<<<(N_NODES + 127) / 128, 256, 0, stream>>>(
        bufB, cnt_in, ell, inv_in, inv_out, W1, b1, bufA);
    layer2_kernel<<<(N_NODES + 127) / 128, 256, 0, stream>>>(
        bufA, cnt_in, ell, inv_in, inv_out, W2, b2, W3, bufB);
    layer3_kernel<<<(N_NODES + 511) / 512, BIGBLK, 0, stream>>>(
        bufB, cnt_in, ell, inv_in, b3, gid, gsum, gcnt);
    finalize_kernel<<<1, 640, 0, stream>>>(gsum, gcnt, out);
}

// Round 15
// 199.698 us; speedup vs baseline: 1.0281x; 1.0281x over previous
//
#include <hip/hip_runtime.h>
#include <hip/hip_fp16.h>

#define N_NODES 100000
#define N_EDGES 1600000
#define N_GRAPHS 64

// ELL build (cap 64; max deg_in <= 48 proven R4). fp16 feature buffers
// (fp32 compute) validated R13: absmax 2.4e-4 << 2.1e-3. R14 lesson: layer3's
// 512-node blocks gave a 196-block grid < 256 CUs -- GRID MUST BE >= 256
// BLOCKS on MI355X. R15: layer3 at 128 nodes/block (782 blocks), same 2-lane
// uint4 gather on 32B-padded p rows (3.2MB, per-XCD L2 resident). Laws:
// random-op count sets scatter cost (R2-R5); per-XCD L2 residency sets gather
// cost (R8/R9); occupancy/coverage sets latency-bound cost (R5/R13/R14); no
// __threadfence in fat grids (R9); traffic cuts alone are neutral (R12).
#define NCHUNK 128
#define CHUNK_E (N_EDGES / NCHUNK)   // 12500
#define NRANGE 2
#define RANGE_N (N_NODES / NRANGE)   // 50000
#define ELL_CAP 64                   // power of 2: start = i<<6
#define SCAN_BLK 256

union H2I { __half2 h2; unsigned int u; };

__device__ inline void acc8h(float* a, uint4 v) {   // 8 halfs -> a[0..8) +=
    H2I t;
    t.u = v.x; float2 f = __half22float2(t.h2); a[0] += f.x; a[1] += f.y;
    t.u = v.y; f = __half22float2(t.h2);        a[2] += f.x; a[3] += f.y;
    t.u = v.z; f = __half22float2(t.h2);        a[4] += f.x; a[5] += f.y;
    t.u = v.w; f = __half22float2(t.h2);        a[6] += f.x; a[7] += f.y;
}

__device__ inline void acc4h(float* a, uint2 v) {   // 4 halfs -> a[0..4) +=
    H2I t;
    t.u = v.x; float2 f = __half22float2(t.h2); a[0] += f.x; a[1] += f.y;
    t.u = v.y; f = __half22float2(t.h2);        a[2] += f.x; a[3] += f.y;
}

// ---------------- fused histogram: dst + src -> packed-u8 partial counts ----------
__global__ __launch_bounds__(1024) void
hist_kernel(const int* __restrict__ dst, const int* __restrict__ src,
            unsigned char* __restrict__ pin8, unsigned char* __restrict__ pout8) {
    __shared__ unsigned int hin[RANGE_N / 4];    // 50KB
    __shared__ unsigned int hout[RANGE_N / 4];   // 50KB
    int c = blockIdx.x >> 1;
    int r = blockIdx.x & 1;
    for (int k = threadIdx.x; k < RANGE_N / 4; k += blockDim.x) { hin[k] = 0; hout[k] = 0; }
    __syncthreads();
    int lo = r * RANGE_N;
    const int4* d4 = (const int4*)(dst + c * CHUNK_E);
    const int4* s4 = (const int4*)(src + c * CHUNK_E);
    for (int k = threadIdx.x; k < CHUNK_E / 4; k += blockDim.x) {
        int4 v = d4[k];
        int d0 = v.x - lo, d1 = v.y - lo, d2 = v.z - lo, d3 = v.w - lo;
        if ((unsigned)d0 < RANGE_N) atomicAdd(&hin[d0 >> 2], 1u << (8 * (d0 & 3)));
        if ((unsigned)d1 < RANGE_N) atomicAdd(&hin[d1 >> 2], 1u << (8 * (d1 & 3)));
        if ((unsigned)d2 < RANGE_N) atomicAdd(&hin[d2 >> 2], 1u << (8 * (d2 & 3)));
        if ((unsigned)d3 < RANGE_N) atomicAdd(&hin[d3 >> 2], 1u << (8 * (d3 & 3)));
        int4 s = s4[k];
        int s0 = s.x - lo, s1 = s.y - lo, s2 = s.z - lo, s3 = s.w - lo;
        if ((unsigned)s0 < RANGE_N) atomicAdd(&hout[s0 >> 2], 1u << (8 * (s0 & 3)));
        if ((unsigned)s1 < RANGE_N) atomicAdd(&hout[s1 >> 2], 1u << (8 * (s1 & 3)));
        if ((unsigned)s2 < RANGE_N) atomicAdd(&hout[s2 >> 2], 1u << (8 * (s2 & 3)));
        if ((unsigned)s3 < RANGE_N) atomicAdd(&hout[s3 >> 2], 1u << (8 * (s3 & 3)));
    }
    __syncthreads();
    unsigned int* pi = (unsigned int*)(pin8 + (size_t)c * N_NODES + lo);
    unsigned int* po = (unsigned int*)(pout8 + (size_t)c * N_NODES + lo);
    for (int k = threadIdx.x; k < RANGE_N / 4; k += blockDim.x) { pi[k] = hin[k]; po[k] = hout[k]; }
}

// ------- per-node chunk-exclusive prefix (u8 in place) + cnt_in/inv_in (+ zero gsum) ----
__global__ void chunkscan_kernel(unsigned char* __restrict__ pin8, int* __restrict__ cnt_in,
                                 float* __restrict__ inv_in, float* __restrict__ gz, int n) {
    if (blockIdx.x == 0) {
        for (int k = threadIdx.x; k < N_GRAPHS * 10 + N_GRAPHS; k += SCAN_BLK) gz[k] = 0.0f;
    }
    int i = blockIdx.x * SCAN_BLK + threadIdx.x;
    if (i >= n) return;
    int s = 0;
#pragma unroll 16
    for (int c = 0; c < NCHUNK; c++) {
        size_t off = (size_t)c * N_NODES + i;
        int v = pin8[off];
        pin8[off] = (unsigned char)s;
        s += v;
    }
    cnt_in[i] = s;
    inv_in[i] = 1.0f / sqrtf(fmaxf((float)s, 1.0f));
}

// ---- place into ELL rows via dual-u16 packed LDS cursors + outdeg/prescale tail ----
__global__ __launch_bounds__(1024) void
place_kernel(const int* __restrict__ src, const int* __restrict__ dst,
             const unsigned char* __restrict__ pin8, int* __restrict__ ell,
             const unsigned char* __restrict__ pout8, const float* __restrict__ x,
             float* __restrict__ inv_out, __half* __restrict__ xs) {
    __shared__ unsigned int cur[RANGE_N / 2];   // dual u16 cursors, 100KB
    int c = blockIdx.x >> 1;
    int r = blockIdx.x & 1;
    int lo = r * RANGE_N;
    const unsigned char* p = pin8 + (size_t)c * N_NODES + lo;
    for (int k = threadIdx.x; k < RANGE_N / 2; k += blockDim.x)
        cur[k] = (unsigned int)p[2 * k] | ((unsigned int)p[2 * k + 1] << 16);
    __syncthreads();
    const int4* d4 = (const int4*)(dst + c * CHUNK_E);
    const int4* s4 = (const int4*)(src + c * CHUNK_E);
    for (int k = threadIdx.x; k < CHUNK_E / 4; k += blockDim.x) {
        int4 dv = d4[k];
        int4 sv = s4[k];
        int d[4] = {dv.x - lo, dv.y - lo, dv.z - lo, dv.w - lo};
        int sarr[4] = {sv.x, sv.y, sv.z, sv.w};
#pragma unroll
        for (int q = 0; q < 4; q++) {
            int dd = d[q];
            if ((unsigned)dd < RANGE_N) {
                unsigned int sh = 16u * (dd & 1);
                unsigned int old = atomicAdd(&cur[dd >> 1], 1u << sh);
                int prefix = (old >> sh) & 0xFFFF;
                ell[((lo + dd) << 6) + prefix] = sarr[q];
            }
        }
    }
    int i = blockIdx.x * blockDim.x + threadIdx.x;
    if (i < N_NODES) {
        int sd = 0;
#pragma unroll 16
        for (int cc = 0; cc < NCHUNK; cc++) sd += pout8[(size_t)cc * N_NODES + i];
        float io = 1.0f / sqrtf(fmaxf((float)sd, 1.0f));
        inv_out[i] = io;
        const float4* x4 = (const float4*)x;
        float4 a = x4[i * 2], b = x4[i * 2 + 1];
        H2I q0, q1, q2, q3;
        q0.h2 = __floats2half2_rn(a.x * io, a.y * io);
        q1.h2 = __floats2half2_rn(a.z * io, a.w * io);
        q2.h2 = __floats2half2_rn(b.x * io, b.y * io);
        q3.h2 = __floats2half2_rn(b.z * io, b.w * io);
        uint4 w = {q0.u, q1.u, q2.u, q3.u};
        ((uint4*)xs)[i] = w;
    }
}

// ---- layer 1: 2 lanes/node (uint2 = 4 halfs each), LDS tile, @W1+b1, relu, *inv_out ----
__global__ __launch_bounds__(256) void
layer1_kernel(const __half* __restrict__ xs, const int* __restrict__ cnt_in,
              const int* __restrict__ ell,
              const float* __restrict__ inv_in, const float* __restrict__ inv_out,
              const float* __restrict__ W1, const float* __restrict__ b1,
              __half* __restrict__ hout) {
    __shared__ float sW[8 * 16];
    __shared__ float sb[16];
    __shared__ float tile[128 * 8];
    if (threadIdx.x < 128) sW[threadIdx.x] = W1[threadIdx.x];
    if (threadIdx.x < 16) sb[threadIdx.x] = b1[threadIdx.x];
    int ii = threadIdx.x >> 1, f = threadIdx.x & 1;
    int i = blockIdx.x * 128 + ii;
    const uint2* xsu = (const uint2*)xs;   // node row = 2 uint2
    float a[4] = {0.f, 0.f, 0.f, 0.f};
    if (i < N_NODES) {
        int start = i << 6, deg = cnt_in[i];
        int k = 0;
        for (; k + 7 < deg; k += 8) {   // 8 uint2 gathers in flight
            int4 I0 = *(const int4*)(ell + start + k);
            int4 I1 = *(const int4*)(ell + start + k + 4);
            uint2 v0 = xsu[I0.x * 2 + f], v1 = xsu[I0.y * 2 + f];
            uint2 v2 = xsu[I0.z * 2 + f], v3 = xsu[I0.w * 2 + f];
            uint2 v4 = xsu[I1.x * 2 + f], v5 = xsu[I1.y * 2 + f];
            uint2 v6 = xsu[I1.z * 2 + f], v7 = xsu[I1.w * 2 + f];
            acc4h(a, v0); acc4h(a, v1); acc4h(a, v2); acc4h(a, v3);
            acc4h(a, v4); acc4h(a, v5); acc4h(a, v6); acc4h(a, v7);
        }
        for (; k < deg; k++) acc4h(a, xsu[ell[start + k] * 2 + f]);
        float inv = inv_in[i];
#pragma unroll
        for (int m = 0; m < 4; m++) a[m] *= inv;
    }
    float4 t = {a[0], a[1], a[2], a[3]};
    ((float4*)tile)[ii * 2 + f] = t;
    __syncthreads();
#pragma unroll
    for (int rep = 0; rep < 8; rep++) {   // 128 nodes x 16 outputs
        int idx = threadIdx.x + rep * 256;
        int i2 = idx >> 4, j = idx & 15;
        int gi = blockIdx.x * 128 + i2;
        if (gi < N_NODES) {
            float o = sb[j];
#pragma unroll
            for (int m = 0; m < 8; m++) o += tile[i2 * 8 + m] * sW[m * 16 + j];
            hout[gi * 16 + j] = __float2half(fmaxf(o, 0.0f) * inv_out[gi]);
        }
    }
}

// ---- layer 2: gather fp16 h (2 lanes/node x uint4) + relu((.)@W2+b2)@W3, *inv_out ----
// p output fp16, PADDED stride 16 halfs (32B row, 3.2MB: per-XCD L2 resident).
__global__ __launch_bounds__(256) void
layer2_kernel(const __half* __restrict__ h, const int* __restrict__ cnt_in,
              const int* __restrict__ ell,
              const float* __restrict__ inv_in, const float* __restrict__ inv_out,
              const float* __restrict__ W2, const float* __restrict__ b2,
              const float* __restrict__ W3, __half* __restrict__ pout) {
    __shared__ float sW2[16 * 32];
    __shared__ float sb2[32];
    __shared__ float sW3[32 * 10];
    __shared__ float tile[128 * 16];    // 8 KB
    __shared__ float otile[128 * 33];   // 16.9 KB, +1 pad
    for (int k = threadIdx.x; k < 512; k += 256) sW2[k] = W2[k];
    if (threadIdx.x < 32) sb2[threadIdx.x] = b2[threadIdx.x];
    for (int k = threadIdx.x; k < 320; k += 256) sW3[k] = W3[k];
    int ii = threadIdx.x >> 1, f = threadIdx.x & 1;   // 2 lanes/node, uint4 each
    int i = blockIdx.x * 128 + ii;
    const uint4* hq = (const uint4*)h;
    float a[8] = {0.f, 0.f, 0.f, 0.f, 0.f, 0.f, 0.f, 0.f};
    if (i < N_NODES) {
        int start = i << 6, deg = cnt_in[i];
        int k = 0;
        for (; k + 7 < deg; k += 8) {
            int4 I0 = *(const int4*)(ell + start + k);
            int4 I1 = *(const int4*)(ell + start + k + 4);
            uint4 v0 = hq[I0.x * 2 + f], v1 = hq[I0.y * 2 + f];
            uint4 v2 = hq[I0.z * 2 + f], v3 = hq[I0.w * 2 + f];
            uint4 v4 = hq[I1.x * 2 + f], v5 = hq[I1.y * 2 + f];
            uint4 v6 = hq[I1.z * 2 + f], v7 = hq[I1.w * 2 + f];
            acc8h(a, v0); acc8h(a, v1); acc8h(a, v2); acc8h(a, v3);
            acc8h(a, v4); acc8h(a, v5); acc8h(a, v6); acc8h(a, v7);
        }
        for (; k < deg; k++) acc8h(a, hq[ell[start + k] * 2 + f]);
        float inv = inv_in[i];
#pragma unroll
        for (int m = 0; m < 8; m++) a[m] *= inv;
    }
    float4 t0 = {a[0], a[1], a[2], a[3]}, t1 = {a[4], a[5], a[6], a[7]};
    ((float4*)tile)[ii * 4 + f * 2] = t0;
    ((float4*)tile)[ii * 4 + f * 2 + 1] = t1;
    __syncthreads();
#pragma unroll
    for (int rep = 0; rep < 16; rep++) {   // 128 nodes x 32 hidden
        int idx = threadIdx.x + rep * 256;
        int i2 = idx >> 5, kk = idx & 31;
        if (blockIdx.x * 128 + i2 < N_NODES) {
            float o = sb2[kk];
#pragma unroll
            for (int m = 0; m < 16; m++) o += tile[i2 * 16 + m] * sW2[m * 32 + kk];
            otile[i2 * 33 + kk] = fmaxf(o, 0.0f);
        }
    }
    __syncthreads();
#pragma unroll
    for (int rep = 0; rep < 4; rep++) {   // 128 nodes x 8 half2 (pairs 5-7 zero pad)
        int idx = threadIdx.x + rep * 256;
        int i2 = idx >> 3, jp = idx & 7;
        int gi = blockIdx.x * 128 + i2;
        if (gi < N_NODES) {
            H2I q;
            if (jp < 5) {
                int j0 = 2 * jp, j1 = j0 + 1;
                float p0 = 0.0f, p1 = 0.0f;
#pragma unroll
                for (int k2 = 0; k2 < 32; k2++) {
                    float ov = otile[i2 * 33 + k2];
                    p0 += ov * sW3[k2 * 10 + j0];
                    p1 += ov * sW3[k2 * 10 + j1];
                }
                float io = inv_out[gi];
                q.h2 = __floats2half2_rn(p0 * io, p1 * io);
            } else {
                q.u = 0;
            }
            ((unsigned int*)pout)[gi * 8 + jp] = q.u;
        }
    }
}

// ---- layer 3: gather fp16 p (2 lanes/node x uint4, 32B padded row) + *inv_in + b3
// ---- + LDS graph mean + sparse flush. 128 nodes/block -> 782 blocks (R14 bug:
// ---- 512 nodes/block gave 196 blocks < 256 CUs). ----
__global__ __launch_bounds__(256) void
layer3_kernel(const __half* __restrict__ p, const int* __restrict__ cnt_in,
              const int* __restrict__ ell,
              const float* __restrict__ inv_in, const float* __restrict__ b3,
              const int* __restrict__ gid, float* __restrict__ gsum,
              float* __restrict__ gcnt) {
    __shared__ float sb3[10];
    __shared__ float lsum[N_GRAPHS * 10];
    __shared__ float lcnt[N_GRAPHS];
    if (threadIdx.x < 10) sb3[threadIdx.x] = b3[threadIdx.x];
    for (int k = threadIdx.x; k < N_GRAPHS * 10; k += 256) lsum[k] = 0.0f;
    if (threadIdx.x < N_GRAPHS) lcnt[threadIdx.x] = 0.0f;
    __syncthreads();
    int ii = threadIdx.x >> 1, f = threadIdx.x & 1;   // 2 lanes/node, uint4 each
    int i = blockIdx.x * 128 + ii;
    if (i < N_NODES) {
        const uint4* pq = (const uint4*)p;   // node row = 2 uint4 (16 halfs, 10 real)
        float a[8] = {0.f, 0.f, 0.f, 0.f, 0.f, 0.f, 0.f, 0.f};
        int start = i << 6, deg = cnt_in[i];
        int k = 0;
        for (; k + 7 < deg; k += 8) {
            int4 I0 = *(const int4*)(ell + start + k);
            int4 I1 = *(const int4*)(ell + start + k + 4);
            uint4 v0 = pq[I0.x * 2 + f], v1 = pq[I0.y * 2 + f];
            uint4 v2 = pq[I0.z * 2 + f], v3 = pq[I0.w * 2 + f];
            uint4 v4 = pq[I1.x * 2 + f], v5 = pq[I1.y * 2 + f];
            uint4 v6 = pq[I1.z * 2 + f], v7 = pq[I1.w * 2 + f];
            acc8h(a, v0); acc8h(a, v1); acc8h(a, v2); acc8h(a, v3);
            acc8h(a, v4); acc8h(a, v5); acc8h(a, v6); acc8h(a, v7);
        }
        for (; k < deg; k++) acc8h(a, pq[ell[start + k] * 2 + f]);
        float inv = inv_in[i];
        int g = gid[i];
        if (f == 0) {   // features 0..7
#pragma unroll
            for (int c = 0; c < 8; c++)
                atomicAdd(&lsum[g * 10 + c], a[c] * inv + sb3[c]);
        } else {        // features 8,9 (halfs 10..15 are zero pad)
            atomicAdd(&lsum[g * 10 + 8], a[0] * inv + sb3[8]);
            atomicAdd(&lsum[g * 10 + 9], a[1] * inv + sb3[9]);
            atomicAdd(&lcnt[g], 1.0f);
        }
    }
    __syncthreads();
    for (int k = threadIdx.x; k < N_GRAPHS * 10; k += 256) {
        float v = lsum[k];
        if (v != 0.0f) atomicAdd(&gsum[k], v);
    }
    if (threadIdx.x < N_GRAPHS) {
        float v = lcnt[threadIdx.x];
        if (v != 0.0f) atomicAdd(&gcnt[threadIdx.x], v);
    }
}

__global__ void finalize_kernel(const float* __restrict__ gsum, const float* __restrict__ gcnt,
                                float* __restrict__ out) {
    int t = blockIdx.x * blockDim.x + threadIdx.x;
    if (t < N_GRAPHS * 10) {
        int g = t / 10;
        out[t] = gsum[t] / fmaxf(gcnt[g], 1.0f);
    }
}

extern "C" void kernel_launch(void* const* d_in, const int* in_sizes, int n_in,
                              void* d_out, int out_size, void* d_ws, size_t ws_size,
                              hipStream_t stream) {
    const float* n_feat = (const float*)d_in[0];  // [N,8]
    const int*   src    = (const int*)d_in[1];    // [E]
    const int*   dst    = (const int*)d_in[2];    // [E]
    const int*   gid    = (const int*)d_in[3];    // [N]
    const float* W1     = (const float*)d_in[4];  // [8,16]
    const float* b1     = (const float*)d_in[5];
    const float* W2     = (const float*)d_in[6];  // [16,32]
    const float* b2     = (const float*)d_in[7];
    const float* W3     = (const float*)d_in[8];  // [32,10]
    const float* b3     = (const float*)d_in[9];
    float* out = (float*)d_out;

    // ---- workspace layout (~60 MB of 256 MiB) ----
    float* ws      = (float*)d_ws;
    float* inv_out = ws;
    float* inv_in  = ws + N_NODES;
    __half* bufA   = (__half*)(ws + 2 * N_NODES);    // h: 16N halfs
    __half* bufB   = (__half*)(ws + 10 * N_NODES);   // xs: 8N halfs / p: 16N halfs
    float* gsum    = ws + 18 * N_NODES;
    float* gcnt    = gsum + N_GRAPHS * 10;
    int* cnt_in    = (int*)(gcnt + N_GRAPHS);
    int* ell       = cnt_in + N_NODES;                          // 64N ints
    unsigned char* pin8  = (unsigned char*)(ell + (size_t)ELL_CAP * N_NODES);
    unsigned char* pout8 = pin8 + (size_t)NCHUNK * N_NODES;

    const int BIGBLK = 1024;
    const int NPARTS = (N_NODES + SCAN_BLK - 1) / SCAN_BLK;  // 391
    const int TGRID = NCHUNK * NRANGE;                        // 256

    // ---- atomic-free graph build, no scan (3 dispatches) ----
    hist_kernel<<<TGRID, BIGBLK, 0, stream>>>(dst, src, pin8, pout8);
    chunkscan_kernel<<<NPARTS, SCAN_BLK, 0, stream>>>(pin8, cnt_in, inv_in, gsum, N_NODES);
    place_kernel<<<TGRID, BIGBLK, 0, stream>>>(src, dst, pin8, ell, pout8, n_feat,
                                               inv_out, bufB);

    // ---- three fused layers + finalize (4 dispatches) ----
    layer1_kernel<<<(N_NODES + 127) / 128, 256, 0, stream>>>(
        bufB, cnt_in, ell, inv_in, inv_out, W1, b1, bufA);
    layer2_kernel<<<(N_NODES + 127) / 128, 256, 0, stream>>>(
        bufA, cnt_in, ell, inv_in, inv_out, W2, b2, W3, bufB);
    layer3_kernel<<<(N_NODES + 127) / 128, 256, 0, stream>>>(
        bufB, cnt_in, ell, inv_in, b3, gid, gsum, gcnt);
    finalize_kernel<<<1, 640, 0, stream>>>(gsum, gcnt, out);
}